// Round 4
// baseline (773.791 us; speedup 1.0000x reference)
//
#include <hip/hip_runtime.h>
#include <math.h>

#define NN 50000
#define NE 800000
#define EMB 128
#define GH 64
#define BB 64
#define TT 200
#define HH 128
#define G4 512
#define IND 134

__device__ __forceinline__ float sigf(float x) { return 1.0f / (1.0f + __expf(-x)); }
__device__ __forceinline__ float tanhf_(float x) { return 1.0f - 2.0f / (__expf(2.0f * x) + 1.0f); }
__device__ __forceinline__ void fma4(float4& a, float s, const float4 w) {
    a.x += s * w.x; a.y += s * w.y; a.z += s * w.z; a.w += s * w.w;
}
__device__ __forceinline__ float rlf(float x, int k) {
    return __int_as_float(__builtin_amdgcn_readlane(__float_as_int(x), k));
}

// ---------------- CSR build ----------------
__global__ void hist_kernel(const int* __restrict__ ei, const float* __restrict__ ew,
                            int* __restrict__ cnt, float* __restrict__ degw) {
    int e = blockIdx.x * 256 + threadIdx.x;
    if (e >= NE) return;
    int d = ei[NE + e];
    atomicAdd(&cnt[d], 1);
    atomicAdd(&degw[d], ew[e]);
}

__global__ void dinv_kernel(const float* __restrict__ degw, float* __restrict__ dinv) {
    int n = blockIdx.x * 256 + threadIdx.x;
    if (n >= NN) return;
    dinv[n] = rsqrtf(degw[n] + 1.0f);   // +1 self loop
}

__global__ __launch_bounds__(1024) void scan1_kernel(const int* __restrict__ cnt,
                                                     int* __restrict__ rs, int* __restrict__ partials) {
    __shared__ int s[1024];
    int gid = blockIdx.x * 1024 + threadIdx.x;
    int v = (gid < NN) ? cnt[gid] : 0;
    s[threadIdx.x] = v;
    __syncthreads();
    for (int off = 1; off < 1024; off <<= 1) {
        int add = (threadIdx.x >= (unsigned)off) ? s[threadIdx.x - off] : 0;
        __syncthreads();
        s[threadIdx.x] += add;
        __syncthreads();
    }
    if (gid < NN) rs[gid] = s[threadIdx.x] - v;  // exclusive
    if (threadIdx.x == 1023) partials[blockIdx.x] = s[1023];
}

__global__ void scan2_kernel(int* __restrict__ partials, int nblk) {
    if (threadIdx.x == 0) {
        int acc = 0;
        for (int i = 0; i < nblk; ++i) { int v = partials[i]; partials[i] = acc; acc += v; }
    }
}

__global__ __launch_bounds__(1024) void scan3_kernel(const int* __restrict__ partials,
                                                     int* __restrict__ rs, int* __restrict__ cursor) {
    int gid = blockIdx.x * 1024 + threadIdx.x;
    if (gid < NN) {
        int v = rs[gid] + partials[gid >> 10];
        rs[gid] = v;
        cursor[gid] = v;
    }
    if (gid == 0) rs[NN] = NE;
}

__global__ void fill_kernel(const int* __restrict__ ei, const float* __restrict__ ew,
                            const float* __restrict__ dinv, int* __restrict__ cursor,
                            int* __restrict__ ssrc, float* __restrict__ sw) {
    int e = blockIdx.x * 256 + threadIdx.x;
    if (e >= NE) return;
    int s = ei[e], d = ei[NE + e];
    int pos = atomicAdd(&cursor[d], 1);
    ssrc[pos] = s;
    sw[pos] = ew[e] * dinv[s] * dinv[d];
}

// ---------------- GCN layer 1 GEMM (fused concat, 134 -> 64) ----------------
__global__ __launch_bounds__(256) void gemm1_kernel(const float* __restrict__ coords,
                                                    const float* __restrict__ temporal,
                                                    const float* __restrict__ emb,
                                                    const float* __restrict__ W1,
                                                    float* __restrict__ h1) {
    __shared__ __align__(16) float wl[IND][GH];
    for (int i = threadIdx.x; i < IND * GH / 4; i += 256)
        ((float4*)wl)[i] = ((const float4*)W1)[i];
    __syncthreads();
    int n = blockIdx.x * 256 + threadIdx.x;
    if (n >= NN) return;
    float4 acc[16];
    float c0 = coords[2 * n], c1 = coords[2 * n + 1];
#pragma unroll
    for (int j = 0; j < 16; ++j) {
        float4 wa = *(const float4*)&wl[0][j * 4];
        float4 wb = *(const float4*)&wl[1][j * 4];
        float4 a;
        a.x = c0 * wa.x + c1 * wb.x; a.y = c0 * wa.y + c1 * wb.y;
        a.z = c0 * wa.z + c1 * wb.z; a.w = c0 * wa.w + c1 * wb.w;
        acc[j] = a;
    }
    const float4* er = (const float4*)(emb + (size_t)n * EMB);
#pragma unroll 2
    for (int k4 = 0; k4 < 32; ++k4) {
        float4 v = er[k4];
        int k = 2 + k4 * 4;
#pragma unroll
        for (int j = 0; j < 16; ++j) {
            fma4(acc[j], v.x, *(const float4*)&wl[k][j * 4]);
            fma4(acc[j], v.y, *(const float4*)&wl[k + 1][j * 4]);
            fma4(acc[j], v.z, *(const float4*)&wl[k + 2][j * 4]);
            fma4(acc[j], v.w, *(const float4*)&wl[k + 3][j * 4]);
        }
    }
    float t0 = temporal[4 * n], t1 = temporal[4 * n + 1], t2 = temporal[4 * n + 2], t3 = temporal[4 * n + 3];
#pragma unroll
    for (int j = 0; j < 16; ++j) {
        fma4(acc[j], t0, *(const float4*)&wl[130][j * 4]);
        fma4(acc[j], t1, *(const float4*)&wl[131][j * 4]);
        fma4(acc[j], t2, *(const float4*)&wl[132][j * 4]);
        fma4(acc[j], t3, *(const float4*)&wl[133][j * 4]);
        *(float4*)&h1[(size_t)n * GH + j * 4] = acc[j];
    }
}

// ---------------- symmetric-norm aggregation (64 features, CSR) ----------------
__global__ __launch_bounds__(256) void agg_kernel(const float* __restrict__ hin,
                                                  const int* __restrict__ rs,
                                                  const int* __restrict__ ssrc,
                                                  const float* __restrict__ sw,
                                                  const float* __restrict__ dinv,
                                                  const float* __restrict__ bias, int relu,
                                                  float* __restrict__ hout) {
    int lane = threadIdx.x & 63;
    int wid = threadIdx.x >> 6;
    int n = blockIdx.x * 4 + wid;
    if (n >= NN) return;
    float dv = dinv[n];
    float acc = hin[(size_t)n * GH + lane] * (dv * dv);  // self loop
    int i = rs[n], e1 = rs[n + 1];
    for (; i + 3 < e1; i += 4) {
        int s0 = ssrc[i], s1 = ssrc[i + 1], s2 = ssrc[i + 2], s3 = ssrc[i + 3];
        float w0 = sw[i], w1 = sw[i + 1], w2 = sw[i + 2], w3 = sw[i + 3];
        float a0 = hin[(size_t)s0 * GH + lane];
        float a1 = hin[(size_t)s1 * GH + lane];
        float a2 = hin[(size_t)s2 * GH + lane];
        float a3 = hin[(size_t)s3 * GH + lane];
        acc += a0 * w0 + a1 * w1 + a2 * w2 + a3 * w3;
    }
    for (; i < e1; ++i) acc += hin[(size_t)ssrc[i] * GH + lane] * sw[i];
    if (bias) acc += bias[lane];
    if (relu) acc = fmaxf(acc, 0.0f);
    hout[(size_t)n * GH + lane] = acc;
}

// ---------------- GCN layer 2 GEMM (64 -> 128) + bias ----------------
__global__ __launch_bounds__(256) void gemm2_kernel(const float* __restrict__ a2,
                                                    const float* __restrict__ W2,
                                                    const float* __restrict__ b2,
                                                    float* __restrict__ z2) {
    __shared__ __align__(16) float wl[GH][64];
    int j0 = blockIdx.y * 64;
    for (int i = threadIdx.x; i < GH * 16; i += 256) {
        int k = i >> 4, j4 = i & 15;
        *(float4*)&wl[k][j4 * 4] = *(const float4*)&W2[(size_t)k * EMB + j0 + j4 * 4];
    }
    __syncthreads();
    int n = blockIdx.x * 256 + threadIdx.x;
    if (n >= NN) return;
    float4 acc[16];
#pragma unroll
    for (int j = 0; j < 16; ++j) acc[j] = *(const float4*)&b2[j0 + j * 4];
    const float4* ar = (const float4*)(a2 + (size_t)n * GH);
#pragma unroll 2
    for (int k4 = 0; k4 < 16; ++k4) {
        float4 v = ar[k4];
        int k = k4 * 4;
#pragma unroll
        for (int j = 0; j < 16; ++j) {
            fma4(acc[j], v.x, *(const float4*)&wl[k][j * 4]);
            fma4(acc[j], v.y, *(const float4*)&wl[k + 1][j * 4]);
            fma4(acc[j], v.z, *(const float4*)&wl[k + 2][j * 4]);
            fma4(acc[j], v.w, *(const float4*)&wl[k + 3][j * 4]);
        }
    }
#pragma unroll
    for (int j = 0; j < 16; ++j)
        *(float4*)&z2[(size_t)n * EMB + j0 + j * 4] = acc[j];
}

// ---------------- gather sequence embeddings ----------------
__global__ void gather_kernel(const int* __restrict__ seq, const float* __restrict__ z2,
                              float* __restrict__ se) {
    int idx = blockIdx.x * 256 + threadIdx.x;
    if (idx >= BB * TT * 32) return;
    int r = idx >> 5, q = idx & 31;
    int node = seq[r];
    ((float4*)se)[(size_t)r * 32 + q] = ((const float4*)z2)[(size_t)node * 32 + q];
}

// ---------------- pre-GEMM: x @ w_ih.T + biases, layout [T][B][512] ----------------
__global__ __launch_bounds__(256) void pregemm_kernel(const float* __restrict__ se,
                                                      const float* __restrict__ w_ih_f,
                                                      const float* __restrict__ w_ih_b,
                                                      const float* __restrict__ b_ih_f,
                                                      const float* __restrict__ b_hh_f,
                                                      const float* __restrict__ b_ih_b,
                                                      const float* __restrict__ b_hh_b,
                                                      const int* __restrict__ lengths,
                                                      float* __restrict__ xpf,
                                                      float* __restrict__ xpb) {
    int dir = blockIdx.z;
    const float* w_ih = dir ? w_ih_b : w_ih_f;
    int u0 = blockIdx.y * 64;
    __shared__ __align__(16) float wl[64][EMB];
    __shared__ float bs[64];
    {
        const float4* src = (const float4*)(w_ih + (size_t)u0 * EMB);
        for (int i = threadIdx.x; i < 64 * EMB / 4; i += 256) ((float4*)wl)[i] = src[i];
        if (threadIdx.x < 64) {
            int u = u0 + threadIdx.x;
            bs[threadIdx.x] = dir ? (b_ih_b[u] + b_hh_b[u]) : (b_ih_f[u] + b_hh_f[u]);
        }
    }
    __syncthreads();
    int m = blockIdx.x * 256 + threadIdx.x;  // m = t*64 + b
    if (m >= TT * BB) return;
    int t = m >> 6, b = m & 63;
    int tsrc = t;
    if (dir) {
        int len = lengths[b];
        if (t >= len) return;
        tsrc = len - 1 - t;
    }
    const float4* row = (const float4*)(se + ((size_t)b * TT + tsrc) * EMB);
    float accs[64];
#pragma unroll
    for (int j = 0; j < 64; ++j) accs[j] = bs[j];
#pragma unroll 2
    for (int k4 = 0; k4 < 32; ++k4) {
        float4 xv = row[k4];
#pragma unroll
        for (int j = 0; j < 64; ++j) {
            float4 wv = *(const float4*)&wl[j][k4 * 4];
            accs[j] += xv.x * wv.x + xv.y * wv.y + xv.z * wv.z + xv.w * wv.w;
        }
    }
    float* xp = dir ? xpb : xpf;
#pragma unroll
    for (int j4 = 0; j4 < 16; ++j4) {
        float4 o = make_float4(accs[j4 * 4], accs[j4 * 4 + 1], accs[j4 * 4 + 2], accs[j4 * 4 + 3]);
        *(float4*)&xp[(size_t)m * G4 + u0 + j4 * 4] = o;
    }
}

// ---------------- LSTM recurrence ----------------
// Round-3 diagnosis: old structure was LDS-ISSUE-BOUND: 512 thr x 32
// ds_read_b128 broadcast h-reads = 256 LDS instr/step x ~12cyc = 3072 cyc
// = 1.28us/step on the per-CU LDS unit (matches measured 1.13us/step;
// VALUBusy 16% = 512 VALU cyc / 3072). Weight residency was irrelevant.
// New structure: 1024 threads. Waves 0-7 (p=0) handle k in [0,64),
// waves 8-15 (p=1) k in [64,128). Lane owns output r = g*128+u with 64
// weights (16 float4 - allocator-safe live set; 128 caused AGPR/scratch
// demotion twice). h broadcast via v_readlane from a per-lane h fragment
// (ONE ds_read_b32/lane/step). Partial sums combined through LDS; quad
// shfl butterfly finishes gates.
#define LSTM_LW(i) float4 W##i = wr[i]; \
    asm volatile("" : "+v"(W##i.x), "+v"(W##i.y), "+v"(W##i.z), "+v"(W##i.w));
#define LSTM_RLFMA(i) { \
    float s0 = rlf(hfrag, 4*i+0); a0 += s0 * W##i.x; \
    float s1 = rlf(hfrag, 4*i+1); a1 += s1 * W##i.y; \
    float s2 = rlf(hfrag, 4*i+2); a2 += s2 * W##i.z; \
    float s3 = rlf(hfrag, 4*i+3); a3 += s3 * W##i.w; }

__global__ __launch_bounds__(1024, 4) void lstm_kernel(const float* __restrict__ xpf,
                                                       const float* __restrict__ xpb,
                                                       const float* __restrict__ w_hh_f,
                                                       const float* __restrict__ w_hh_b,
                                                       const int* __restrict__ lengths,
                                                       float* __restrict__ hfo,
                                                       float* __restrict__ hbo) {
    int chain = blockIdx.x;
    int dir = chain & 1, b = chain >> 1;
    const float* w_hh = dir ? w_hh_b : w_hh_f;
    const float* xp = dir ? xpb : xpf;
    float* ho = dir ? hbo : hfo;
    int tid = threadIdx.x;
    int wv = tid >> 6;        // wave 0..15
    int lam = tid & 63;
    int p = wv >> 3;          // k-half: 0 or 1
    int wj = wv & 7;
    int j = wj * 64 + lam;    // internal output index 0..511
    int g = lam & 3;          // gate 0..3 (i,f,g,o)
    int u = j >> 2;           // unit 0..127
    int r = g * HH + u;       // PyTorch row index in 4H dim
    int len = lengths[b];

    const float4* wr = (const float4*)(w_hh + (size_t)r * HH + p * 64);
    LSTM_LW(0) LSTM_LW(1) LSTM_LW(2) LSTM_LW(3) LSTM_LW(4) LSTM_LW(5) LSTM_LW(6) LSTM_LW(7)
    LSTM_LW(8) LSTM_LW(9) LSTM_LW(10) LSTM_LW(11) LSTM_LW(12) LSTM_LW(13) LSTM_LW(14) LSTM_LW(15)

    __shared__ float hl[HH];
    __shared__ float part[G4];
    if (tid < HH) hl[tid] = 0.0f;
    __syncthreads();

    const float* xpt = xp + (size_t)b * G4 + r;
    float cst = 0.0f;
    float xcur = (p == 0) ? xpt[0] : 0.0f;
    for (int t = 0; t < len; ++t) {
        float hfrag = hl[(p << 6) + lam];     // lane lam holds h[p*64+lam]
        float xnext = (p == 0 && t + 1 < len) ? xpt[(size_t)(t + 1) * (BB * G4)] : 0.0f;
        float a0 = 0.0f, a1 = 0.0f, a2 = 0.0f, a3 = 0.0f;
        LSTM_RLFMA(0) LSTM_RLFMA(1) LSTM_RLFMA(2) LSTM_RLFMA(3)
        LSTM_RLFMA(4) LSTM_RLFMA(5) LSTM_RLFMA(6) LSTM_RLFMA(7)
        LSTM_RLFMA(8) LSTM_RLFMA(9) LSTM_RLFMA(10) LSTM_RLFMA(11)
        LSTM_RLFMA(12) LSTM_RLFMA(13) LSTM_RLFMA(14) LSTM_RLFMA(15)
        float accp = (a0 + a1) + (a2 + a3);
        if (p) part[j] = accp;                // p1 waves publish partial
        __syncthreads();
        if (p == 0) {
            float acc = accp + part[j] + xcur;   // full pre-activation for (g,u)
            float a_own = (g == 2) ? tanhf_(acc) : sigf(acc);
            float sb = __shfl_xor(a_own, 1, 64);
            float sc = __shfl_xor(a_own, 2, 64);
            float sd = __shfl_xor(sb, 2, 64);
            float si = (g == 0) ? a_own : (g == 1) ? sb : (g == 2) ? sc : sd;
            float sf = (g == 0) ? sb : (g == 1) ? a_own : (g == 2) ? sd : sc;
            float sg = (g == 0) ? sc : (g == 1) ? sd : (g == 2) ? a_own : sb;
            float so = (g == 0) ? sd : (g == 1) ? sc : (g == 2) ? sb : a_own;
            cst = sf * cst + si * sg;
            float h = so * tanhf_(cst);
            if (g == 0) {
                hl[u] = h;
                int tt = dir ? (len - 1 - t) : t;
                ho[((size_t)b * TT + tt) * HH + u] = h;
            }
        }
        __syncthreads();
        xcur = xnext;
    }
}

// ---------------- masked attention pooling ----------------
__global__ __launch_bounds__(256) void attn_kernel(const float* __restrict__ hf,
                                                   const float* __restrict__ hb,
                                                   const float* __restrict__ attn_w,
                                                   const float* __restrict__ attn_b,
                                                   const int* __restrict__ lengths,
                                                   float* __restrict__ ctx) {
    int b = blockIdx.x;
    int tid = threadIdx.x;
    int len = lengths[b];
    __shared__ __align__(16) float wl[256];
    __shared__ float pl[256];
    __shared__ float red[256];
    wl[tid] = attn_w[tid];
    __syncthreads();
    float sc = -3.0e38f;
    if (tid < len) {
        const float4* rf = (const float4*)(hf + ((size_t)b * TT + tid) * HH);
        const float4* rb = (const float4*)(hb + ((size_t)b * TT + tid) * HH);
        const float4* w4 = (const float4*)wl;
        float s = attn_b[0];
        for (int k4 = 0; k4 < 32; ++k4) {
            float4 a = rf[k4], ww = w4[k4];
            s += a.x * ww.x + a.y * ww.y + a.z * ww.z + a.w * ww.w;
        }
        for (int k4 = 0; k4 < 32; ++k4) {
            float4 a = rb[k4], ww = w4[32 + k4];
            s += a.x * ww.x + a.y * ww.y + a.z * ww.z + a.w * ww.w;
        }
        sc = s;
    }
    red[tid] = sc;
    __syncthreads();
    for (int off = 128; off > 0; off >>= 1) {
        if (tid < off) red[tid] = fmaxf(red[tid], red[tid + off]);
        __syncthreads();
    }
    float mx = red[0];
    __syncthreads();
    float e = (tid < len) ? __expf(sc - mx) : 0.0f;
    red[tid] = e;
    __syncthreads();
    for (int off = 128; off > 0; off >>= 1) {
        if (tid < off) red[tid] += red[tid + off];
        __syncthreads();
    }
    float inv = 1.0f / red[0];
    pl[tid] = e * inv;
    __syncthreads();
    float acc = 0.0f;
    const float* basep = (tid < HH) ? (hf + (size_t)b * TT * HH + tid)
                                    : (hb + (size_t)b * TT * HH + (tid - HH));
#pragma unroll 4
    for (int t = 0; t < len; ++t) acc += pl[t] * basep[(size_t)t * HH];
    ctx[(size_t)b * 256 + tid] = acc;
}

// ---------------- final FC: [64,256] @ [256,N] + b ----------------
__global__ __launch_bounds__(256) void fc_kernel(const float* __restrict__ ctx,
                                                 const float* __restrict__ fc_w,
                                                 const float* __restrict__ fc_b,
                                                 float* __restrict__ out) {
    __shared__ __align__(16) float cl[64][256];
    for (int i = threadIdx.x; i < 64 * 256 / 4; i += 256)
        ((float4*)cl)[i] = ((const float4*)ctx)[i];
    __syncthreads();
    int nb = threadIdx.x & 63;
    int bq = threadIdx.x >> 6;
    int n = blockIdx.x * 64 + nb;
    if (n >= NN) return;
    float acc[16];
#pragma unroll
    for (int i = 0; i < 16; ++i) acc[i] = 0.0f;
#pragma unroll 2
    for (int k4 = 0; k4 < 64; ++k4) {
        int k = k4 * 4;
        float w0 = fc_w[(size_t)k * NN + n];
        float w1 = fc_w[(size_t)(k + 1) * NN + n];
        float w2 = fc_w[(size_t)(k + 2) * NN + n];
        float w3 = fc_w[(size_t)(k + 3) * NN + n];
#pragma unroll
        for (int i = 0; i < 16; ++i) {
            float4 cv = *(const float4*)&cl[bq * 16 + i][k];
            acc[i] += cv.x * w0 + cv.y * w1 + cv.z * w2 + cv.w * w3;
        }
    }
    float fb = fc_b[n];
#pragma unroll
    for (int i = 0; i < 16; ++i)
        out[(size_t)(bq * 16 + i) * NN + n] = acc[i] + fb;
}

// ---------------- host launcher ----------------
extern "C" void kernel_launch(void* const* d_in, const int* in_sizes, int n_in,
                              void* d_out, int out_size, void* d_ws, size_t ws_size,
                              hipStream_t stream) {
    const float* x_coords   = (const float*)d_in[0];
    const float* temporal   = (const float*)d_in[1];
    const int*   edge_index = (const int*)d_in[2];
    const float* edge_w     = (const float*)d_in[3];
    const int*   seq        = (const int*)d_in[4];
    const int*   lengths    = (const int*)d_in[5];
    const float* node_emb   = (const float*)d_in[6];
    const float* gcn1_w     = (const float*)d_in[7];
    const float* gcn1_b     = (const float*)d_in[8];
    const float* gcn2_w     = (const float*)d_in[9];
    const float* gcn2_b     = (const float*)d_in[10];
    const float* w_ih_f     = (const float*)d_in[11];
    const float* w_hh_f     = (const float*)d_in[12];
    const float* b_ih_f     = (const float*)d_in[13];
    const float* b_hh_f     = (const float*)d_in[14];
    const float* w_ih_b     = (const float*)d_in[15];
    const float* w_hh_b     = (const float*)d_in[16];
    const float* b_ih_b     = (const float*)d_in[17];
    const float* b_hh_b     = (const float*)d_in[18];
    const float* attn_w     = (const float*)d_in[19];
    const float* attn_b     = (const float*)d_in[20];
    const float* fc_w       = (const float*)d_in[21];
    const float* fc_b       = (const float*)d_in[22];
    float* out = (float*)d_out;

    char* base = (char*)d_ws;
    size_t off = 0;
    auto alloc = [&](size_t nbytes) -> void* {
        void* p = base + off;
        off = (off + nbytes + 255) & ~(size_t)255;
        return p;
    };
    int*   cnt     = (int*)alloc((size_t)2 * NN * 4);  // cnt + degw contiguous (one memset)
    float* degw    = (float*)(cnt + NN);
    float* dinv    = (float*)alloc((size_t)NN * 4);
    int*   rs      = (int*)alloc(((size_t)NN + 1) * 4);
    int*   cursor  = (int*)alloc((size_t)NN * 4);
    int*   partials= (int*)alloc(64 * 4);
    int*   ssrc    = (int*)alloc((size_t)NE * 4);
    float* sw      = (float*)alloc((size_t)NE * 4);
    float* h1      = (float*)alloc((size_t)NN * GH * 4);
    float* z1      = (float*)alloc((size_t)NN * GH * 4);
    float* a2      = h1;  // h1 dead after agg1
    float* z2      = (float*)alloc((size_t)NN * EMB * 4);
    float* se      = (float*)alloc((size_t)BB * TT * EMB * 4);
    float* xpf     = (float*)alloc((size_t)TT * BB * G4 * 4);
    float* xpb     = (float*)alloc((size_t)TT * BB * G4 * 4);
    float* hfo     = (float*)alloc((size_t)BB * TT * HH * 4);
    float* hbo     = (float*)alloc((size_t)BB * TT * HH * 4);
    float* ctx     = (float*)alloc((size_t)BB * 256 * 4);
    (void)ws_size; (void)in_sizes; (void)n_in; (void)out_size;

    hipMemsetAsync(cnt, 0, (size_t)2 * NN * 4, stream);

    hist_kernel<<<(NE + 255) / 256, 256, 0, stream>>>(edge_index, edge_w, cnt, degw);
    dinv_kernel<<<(NN + 255) / 256, 256, 0, stream>>>(degw, dinv);
    const int nblk = (NN + 1023) / 1024;  // 49
    scan1_kernel<<<nblk, 1024, 0, stream>>>(cnt, rs, partials);
    scan2_kernel<<<1, 64, 0, stream>>>(partials, nblk);
    scan3_kernel<<<nblk, 1024, 0, stream>>>(partials, rs, cursor);
    fill_kernel<<<(NE + 255) / 256, 256, 0, stream>>>(edge_index, edge_w, dinv, cursor, ssrc, sw);

    gemm1_kernel<<<(NN + 255) / 256, 256, 0, stream>>>(x_coords, temporal, node_emb, gcn1_w, h1);
    agg_kernel<<<(NN + 3) / 4, 256, 0, stream>>>(h1, rs, ssrc, sw, dinv, gcn1_b, 1, z1);
    agg_kernel<<<(NN + 3) / 4, 256, 0, stream>>>(z1, rs, ssrc, sw, dinv, (const float*)nullptr, 0, a2);
    gemm2_kernel<<<dim3((NN + 255) / 256, 2), 256, 0, stream>>>(a2, gcn2_w, gcn2_b, z2);

    gather_kernel<<<(BB * TT * 32 + 255) / 256, 256, 0, stream>>>(seq, z2, se);
    pregemm_kernel<<<dim3(TT * BB / 256, 8, 2), 256, 0, stream>>>(
        se, w_ih_f, w_ih_b, b_ih_f, b_hh_f, b_ih_b, b_hh_b, lengths, xpf, xpb);
    lstm_kernel<<<BB * 2, 1024, 0, stream>>>(xpf, xpb, w_hh_f, w_hh_b, lengths, hfo, hbo);
    attn_kernel<<<BB, 256, 0, stream>>>(hfo, hbo, attn_w, attn_b, lengths, ctx);
    fc_kernel<<<(NN + 63) / 64, 256, 0, stream>>>(ctx, fc_w, fc_b, out);
}

// Round 5
// 764.136 us; speedup vs baseline: 1.0126x; 1.0126x over previous
//
#include <hip/hip_runtime.h>
#include <math.h>

#define NN 50000
#define NE 800000
#define EMB 128
#define GH 64
#define BB 64
#define TT 200
#define HH 128
#define G4 512
#define IND 134

__device__ __forceinline__ float sigf(float x) { return 1.0f / (1.0f + __expf(-x)); }
__device__ __forceinline__ float tanhf_(float x) { return 1.0f - 2.0f / (__expf(2.0f * x) + 1.0f); }
__device__ __forceinline__ void fma4(float4& a, float s, const float4 w) {
    a.x += s * w.x; a.y += s * w.y; a.z += s * w.z; a.w += s * w.w;
}

// ---------------- CSR build ----------------
__global__ void hist_kernel(const int* __restrict__ ei, const float* __restrict__ ew,
                            int* __restrict__ cnt, float* __restrict__ degw) {
    int e = blockIdx.x * 256 + threadIdx.x;
    if (e >= NE) return;
    int d = ei[NE + e];
    atomicAdd(&cnt[d], 1);
    atomicAdd(&degw[d], ew[e]);
}

__global__ void dinv_kernel(const float* __restrict__ degw, float* __restrict__ dinv) {
    int n = blockIdx.x * 256 + threadIdx.x;
    if (n >= NN) return;
    dinv[n] = rsqrtf(degw[n] + 1.0f);   // +1 self loop
}

__global__ __launch_bounds__(1024) void scan1_kernel(const int* __restrict__ cnt,
                                                     int* __restrict__ rs, int* __restrict__ partials) {
    __shared__ int s[1024];
    int gid = blockIdx.x * 1024 + threadIdx.x;
    int v = (gid < NN) ? cnt[gid] : 0;
    s[threadIdx.x] = v;
    __syncthreads();
    for (int off = 1; off < 1024; off <<= 1) {
        int add = (threadIdx.x >= (unsigned)off) ? s[threadIdx.x - off] : 0;
        __syncthreads();
        s[threadIdx.x] += add;
        __syncthreads();
    }
    if (gid < NN) rs[gid] = s[threadIdx.x] - v;  // exclusive
    if (threadIdx.x == 1023) partials[blockIdx.x] = s[1023];
}

__global__ void scan2_kernel(int* __restrict__ partials, int nblk) {
    if (threadIdx.x == 0) {
        int acc = 0;
        for (int i = 0; i < nblk; ++i) { int v = partials[i]; partials[i] = acc; acc += v; }
    }
}

__global__ __launch_bounds__(1024) void scan3_kernel(const int* __restrict__ partials,
                                                     int* __restrict__ rs, int* __restrict__ cursor) {
    int gid = blockIdx.x * 1024 + threadIdx.x;
    if (gid < NN) {
        int v = rs[gid] + partials[gid >> 10];
        rs[gid] = v;
        cursor[gid] = v;
    }
    if (gid == 0) rs[NN] = NE;
}

__global__ void fill_kernel(const int* __restrict__ ei, const float* __restrict__ ew,
                            const float* __restrict__ dinv, int* __restrict__ cursor,
                            int* __restrict__ ssrc, float* __restrict__ sw) {
    int e = blockIdx.x * 256 + threadIdx.x;
    if (e >= NE) return;
    int s = ei[e], d = ei[NE + e];
    int pos = atomicAdd(&cursor[d], 1);
    ssrc[pos] = s;
    sw[pos] = ew[e] * dinv[s] * dinv[d];
}

// ---------------- GCN layer 1 GEMM (fused concat, 134 -> 64) ----------------
__global__ __launch_bounds__(256) void gemm1_kernel(const float* __restrict__ coords,
                                                    const float* __restrict__ temporal,
                                                    const float* __restrict__ emb,
                                                    const float* __restrict__ W1,
                                                    float* __restrict__ h1) {
    __shared__ __align__(16) float wl[IND][GH];
    for (int i = threadIdx.x; i < IND * GH / 4; i += 256)
        ((float4*)wl)[i] = ((const float4*)W1)[i];
    __syncthreads();
    int n = blockIdx.x * 256 + threadIdx.x;
    if (n >= NN) return;
    float4 acc[16];
    float c0 = coords[2 * n], c1 = coords[2 * n + 1];
#pragma unroll
    for (int j = 0; j < 16; ++j) {
        float4 wa = *(const float4*)&wl[0][j * 4];
        float4 wb = *(const float4*)&wl[1][j * 4];
        float4 a;
        a.x = c0 * wa.x + c1 * wb.x; a.y = c0 * wa.y + c1 * wb.y;
        a.z = c0 * wa.z + c1 * wb.z; a.w = c0 * wa.w + c1 * wb.w;
        acc[j] = a;
    }
    const float4* er = (const float4*)(emb + (size_t)n * EMB);
#pragma unroll 2
    for (int k4 = 0; k4 < 32; ++k4) {
        float4 v = er[k4];
        int k = 2 + k4 * 4;
#pragma unroll
        for (int j = 0; j < 16; ++j) {
            fma4(acc[j], v.x, *(const float4*)&wl[k][j * 4]);
            fma4(acc[j], v.y, *(const float4*)&wl[k + 1][j * 4]);
            fma4(acc[j], v.z, *(const float4*)&wl[k + 2][j * 4]);
            fma4(acc[j], v.w, *(const float4*)&wl[k + 3][j * 4]);
        }
    }
    float t0 = temporal[4 * n], t1 = temporal[4 * n + 1], t2 = temporal[4 * n + 2], t3 = temporal[4 * n + 3];
#pragma unroll
    for (int j = 0; j < 16; ++j) {
        fma4(acc[j], t0, *(const float4*)&wl[130][j * 4]);
        fma4(acc[j], t1, *(const float4*)&wl[131][j * 4]);
        fma4(acc[j], t2, *(const float4*)&wl[132][j * 4]);
        fma4(acc[j], t3, *(const float4*)&wl[133][j * 4]);
        *(float4*)&h1[(size_t)n * GH + j * 4] = acc[j];
    }
}

// ---------------- symmetric-norm aggregation (64 features, CSR) ----------------
__global__ __launch_bounds__(256) void agg_kernel(const float* __restrict__ hin,
                                                  const int* __restrict__ rs,
                                                  const int* __restrict__ ssrc,
                                                  const float* __restrict__ sw,
                                                  const float* __restrict__ dinv,
                                                  const float* __restrict__ bias, int relu,
                                                  float* __restrict__ hout) {
    int lane = threadIdx.x & 63;
    int wid = threadIdx.x >> 6;
    int n = blockIdx.x * 4 + wid;
    if (n >= NN) return;
    float dv = dinv[n];
    float acc = hin[(size_t)n * GH + lane] * (dv * dv);  // self loop
    int i = rs[n], e1 = rs[n + 1];
    for (; i + 3 < e1; i += 4) {
        int s0 = ssrc[i], s1 = ssrc[i + 1], s2 = ssrc[i + 2], s3 = ssrc[i + 3];
        float w0 = sw[i], w1 = sw[i + 1], w2 = sw[i + 2], w3 = sw[i + 3];
        float a0 = hin[(size_t)s0 * GH + lane];
        float a1 = hin[(size_t)s1 * GH + lane];
        float a2 = hin[(size_t)s2 * GH + lane];
        float a3 = hin[(size_t)s3 * GH + lane];
        acc += a0 * w0 + a1 * w1 + a2 * w2 + a3 * w3;
    }
    for (; i < e1; ++i) acc += hin[(size_t)ssrc[i] * GH + lane] * sw[i];
    if (bias) acc += bias[lane];
    if (relu) acc = fmaxf(acc, 0.0f);
    hout[(size_t)n * GH + lane] = acc;
}

// ---------------- GCN layer 2 GEMM (64 -> 128) + bias ----------------
__global__ __launch_bounds__(256) void gemm2_kernel(const float* __restrict__ a2,
                                                    const float* __restrict__ W2,
                                                    const float* __restrict__ b2,
                                                    float* __restrict__ z2) {
    __shared__ __align__(16) float wl[GH][64];
    int j0 = blockIdx.y * 64;
    for (int i = threadIdx.x; i < GH * 16; i += 256) {
        int k = i >> 4, j4 = i & 15;
        *(float4*)&wl[k][j4 * 4] = *(const float4*)&W2[(size_t)k * EMB + j0 + j4 * 4];
    }
    __syncthreads();
    int n = blockIdx.x * 256 + threadIdx.x;
    if (n >= NN) return;
    float4 acc[16];
#pragma unroll
    for (int j = 0; j < 16; ++j) acc[j] = *(const float4*)&b2[j0 + j * 4];
    const float4* ar = (const float4*)(a2 + (size_t)n * GH);
#pragma unroll 2
    for (int k4 = 0; k4 < 16; ++k4) {
        float4 v = ar[k4];
        int k = k4 * 4;
#pragma unroll
        for (int j = 0; j < 16; ++j) {
            fma4(acc[j], v.x, *(const float4*)&wl[k][j * 4]);
            fma4(acc[j], v.y, *(const float4*)&wl[k + 1][j * 4]);
            fma4(acc[j], v.z, *(const float4*)&wl[k + 2][j * 4]);
            fma4(acc[j], v.w, *(const float4*)&wl[k + 3][j * 4]);
        }
    }
#pragma unroll
    for (int j = 0; j < 16; ++j)
        *(float4*)&z2[(size_t)n * EMB + j0 + j * 4] = acc[j];
}

// ---------------- gather sequence embeddings ----------------
__global__ void gather_kernel(const int* __restrict__ seq, const float* __restrict__ z2,
                              float* __restrict__ se) {
    int idx = blockIdx.x * 256 + threadIdx.x;
    if (idx >= BB * TT * 32) return;
    int r = idx >> 5, q = idx & 31;
    int node = seq[r];
    ((float4*)se)[(size_t)r * 32 + q] = ((const float4*)z2)[(size_t)node * 32 + q];
}

// ---------------- pre-GEMM: x @ w_ih.T + biases, layout [T][B][512] ----------------
// Register-tiled: thread = 4 m-rows x 8 outputs (acc 32 regs). W-broadcast
// from LDS amortized 4x vs round-1 (which did 2048 LDS b128 reads/thread).
// VALU floor for this GEMM pair is ~44us; LDS issue ~32us overlaps under it.
__global__ __launch_bounds__(256) void pregemm_kernel(const float* __restrict__ se,
                                                      const float* __restrict__ w_ih_f,
                                                      const float* __restrict__ w_ih_b,
                                                      const float* __restrict__ b_ih_f,
                                                      const float* __restrict__ b_hh_f,
                                                      const float* __restrict__ b_ih_b,
                                                      const float* __restrict__ b_hh_b,
                                                      const int* __restrict__ lengths,
                                                      float* __restrict__ xpf,
                                                      float* __restrict__ xpb) {
    int dir = blockIdx.z;
    const float* w_ih = dir ? w_ih_b : w_ih_f;
    int o0 = blockIdx.y * 8;                      // 8 outputs per block
    __shared__ __align__(16) float wl[8][EMB];    // 4 KB
    __shared__ float bs[8];
    {
        int j = threadIdx.x >> 5, k4 = threadIdx.x & 31;
        *(float4*)&wl[j][k4 * 4] = *(const float4*)&w_ih[(size_t)(o0 + j) * EMB + k4 * 4];
        if (threadIdx.x < 8) {
            int uo = o0 + threadIdx.x;
            bs[threadIdx.x] = dir ? (b_ih_b[uo] + b_hh_b[uo]) : (b_ih_f[uo] + b_hh_f[uo]);
        }
    }
    __syncthreads();
    int m0 = blockIdx.x * 1024 + threadIdx.x;
    const float4* rows[4];
    bool vstore[4];
#pragma unroll
    for (int r = 0; r < 4; ++r) {
        int m = m0 + 256 * r;
        bool v = m < TT * BB;
        int mm = v ? m : 0;
        int t = mm >> 6, b = mm & 63;
        int tsrc = t;
        if (dir) {
            int len = lengths[b];
            v = v && (t < len);
            tsrc = v ? (len - 1 - t) : 0;
        }
        vstore[r] = v;
        rows[r] = (const float4*)(se + ((size_t)b * TT + tsrc) * EMB);
    }
    float acc[4][8];
#pragma unroll
    for (int r = 0; r < 4; ++r)
#pragma unroll
        for (int j = 0; j < 8; ++j) acc[r][j] = bs[j];
    for (int k4 = 0; k4 < 32; ++k4) {
        float4 xv0 = rows[0][k4], xv1 = rows[1][k4], xv2 = rows[2][k4], xv3 = rows[3][k4];
#pragma unroll
        for (int j = 0; j < 8; ++j) {
            float4 wv = *(const float4*)&wl[j][k4 * 4];
            acc[0][j] += xv0.x * wv.x + xv0.y * wv.y + xv0.z * wv.z + xv0.w * wv.w;
            acc[1][j] += xv1.x * wv.x + xv1.y * wv.y + xv1.z * wv.z + xv1.w * wv.w;
            acc[2][j] += xv2.x * wv.x + xv2.y * wv.y + xv2.z * wv.z + xv2.w * wv.w;
            acc[3][j] += xv3.x * wv.x + xv3.y * wv.y + xv3.z * wv.z + xv3.w * wv.w;
        }
    }
    float* xp = dir ? xpb : xpf;
#pragma unroll
    for (int r = 0; r < 4; ++r) {
        if (!vstore[r]) continue;
        int m = m0 + 256 * r;
        float4 oa = make_float4(acc[r][0], acc[r][1], acc[r][2], acc[r][3]);
        float4 ob = make_float4(acc[r][4], acc[r][5], acc[r][6], acc[r][7]);
        *(float4*)&xp[(size_t)m * G4 + o0] = oa;
        *(float4*)&xp[(size_t)m * G4 + o0 + 4] = ob;
    }
}

// ---------------- LSTM recurrence (Structure Z) ----------------
// 1024 threads/chain. Thread = (u = tid&127, kq = tid>>7): computes partial
// pre-activations for ALL 4 gates of unit u over k in [16kq,16kq+16).
// W/thread = 64 floats (16 float4, static idx) -> fits under the 128-VGPR
// cap of 16 waves/CU; no butterfly (gates in-thread); h-read is
// wave-uniform b128 broadcast (4/thread); partials combined by 2 waves in
// phase B. Round-1/4 pathologies avoided: no 128-float live set, no
// readlane, no asm pin. part kq-dim padded to 9 to spread LDS banks.
__global__ __launch_bounds__(1024, 4) void lstm_kernel(const float* __restrict__ xpf,
                                                       const float* __restrict__ xpb,
                                                       const float* __restrict__ w_hh_f,
                                                       const float* __restrict__ w_hh_b,
                                                       const int* __restrict__ lengths,
                                                       float* __restrict__ hfo,
                                                       float* __restrict__ hbo) {
    int chain = blockIdx.x;
    int dir = chain & 1, b = chain >> 1;
    const float* w_hh = dir ? w_hh_b : w_hh_f;
    const float* xp = dir ? xpb : xpf;
    float* ho = dir ? hbo : hfo;
    int tid = threadIdx.x;
    int u = tid & 127;
    int kq = tid >> 7;    // 0..7
    int len = lengths[b];

    float4 W[4][4];
#pragma unroll
    for (int g = 0; g < 4; ++g)
#pragma unroll
        for (int j4 = 0; j4 < 4; ++j4)
            W[g][j4] = *(const float4*)&w_hh[(size_t)(g * HH + u) * HH + kq * 16 + j4 * 4];

    __shared__ __align__(16) float hl[HH];
    __shared__ __align__(16) float part[HH][9][4];   // [u][kq(pad 9)][gate]
    if (tid < HH) hl[tid] = 0.0f;
    __syncthreads();

    float cst = 0.0f;
    float x0 = 0.f, x1 = 0.f, x2 = 0.f, x3 = 0.f;
    const float* xpt = xp + (size_t)b * G4 + u;
    if (tid < HH && len > 0) {
        x0 = xpt[0]; x1 = xpt[HH]; x2 = xpt[2 * HH]; x3 = xpt[3 * HH];
    }
    for (int t = 0; t < len; ++t) {
        // phase A: all 16 waves; uniform h broadcast reads
        const float4* h4 = (const float4*)&hl[kq * 16];
        float a0 = 0.f, a1 = 0.f, a2 = 0.f, a3 = 0.f;
#pragma unroll
        for (int j4 = 0; j4 < 4; ++j4) {
            float4 hv = h4[j4];
            a0 += W[0][j4].x * hv.x + W[0][j4].y * hv.y + W[0][j4].z * hv.z + W[0][j4].w * hv.w;
            a1 += W[1][j4].x * hv.x + W[1][j4].y * hv.y + W[1][j4].z * hv.z + W[1][j4].w * hv.w;
            a2 += W[2][j4].x * hv.x + W[2][j4].y * hv.y + W[2][j4].z * hv.z + W[2][j4].w * hv.w;
            a3 += W[3][j4].x * hv.x + W[3][j4].y * hv.y + W[3][j4].z * hv.z + W[3][j4].w * hv.w;
        }
        *(float4*)&part[u][kq][0] = make_float4(a0, a1, a2, a3);
        __syncthreads();
        // phase B: 2 waves finish unit u
        if (tid < HH) {
            float n0 = 0.f, n1 = 0.f, n2 = 0.f, n3 = 0.f;
            if (t + 1 < len) {
                const float* xn = xpt + (size_t)(t + 1) * (BB * G4);
                n0 = xn[0]; n1 = xn[HH]; n2 = xn[2 * HH]; n3 = xn[3 * HH];
            }
            float s0 = x0, s1 = x1, s2 = x2, s3 = x3;
#pragma unroll
            for (int q = 0; q < 8; ++q) {
                float4 p = *(const float4*)&part[u][q][0];
                s0 += p.x; s1 += p.y; s2 += p.z; s3 += p.w;
            }
            float gi = sigf(s0), gf = sigf(s1), gg = tanhf_(s2), go = sigf(s3);
            cst = gf * cst + gi * gg;
            float h = go * tanhf_(cst);
            hl[u] = h;
            int tt = dir ? (len - 1 - t) : t;
            ho[((size_t)b * TT + tt) * HH + u] = h;
            x0 = n0; x1 = n1; x2 = n2; x3 = n3;
        }
        __syncthreads();
    }
}

// ---------------- masked attention pooling ----------------
__global__ __launch_bounds__(256) void attn_kernel(const float* __restrict__ hf,
                                                   const float* __restrict__ hb,
                                                   const float* __restrict__ attn_w,
                                                   const float* __restrict__ attn_b,
                                                   const int* __restrict__ lengths,
                                                   float* __restrict__ ctx) {
    int b = blockIdx.x;
    int tid = threadIdx.x;
    int len = lengths[b];
    __shared__ __align__(16) float wl[256];
    __shared__ float pl[256];
    __shared__ float red[256];
    wl[tid] = attn_w[tid];
    __syncthreads();
    float sc = -3.0e38f;
    if (tid < len) {
        const float4* rf = (const float4*)(hf + ((size_t)b * TT + tid) * HH);
        const float4* rb = (const float4*)(hb + ((size_t)b * TT + tid) * HH);
        const float4* w4 = (const float4*)wl;
        float s = attn_b[0];
        for (int k4 = 0; k4 < 32; ++k4) {
            float4 a = rf[k4], ww = w4[k4];
            s += a.x * ww.x + a.y * ww.y + a.z * ww.z + a.w * ww.w;
        }
        for (int k4 = 0; k4 < 32; ++k4) {
            float4 a = rb[k4], ww = w4[32 + k4];
            s += a.x * ww.x + a.y * ww.y + a.z * ww.z + a.w * ww.w;
        }
        sc = s;
    }
    red[tid] = sc;
    __syncthreads();
    for (int off = 128; off > 0; off >>= 1) {
        if (tid < off) red[tid] = fmaxf(red[tid], red[tid + off]);
        __syncthreads();
    }
    float mx = red[0];
    __syncthreads();
    float e = (tid < len) ? __expf(sc - mx) : 0.0f;
    red[tid] = e;
    __syncthreads();
    for (int off = 128; off > 0; off >>= 1) {
        if (tid < off) red[tid] += red[tid + off];
        __syncthreads();
    }
    float inv = 1.0f / red[0];
    pl[tid] = e * inv;
    __syncthreads();
    float acc = 0.0f;
    const float* basep = (tid < HH) ? (hf + (size_t)b * TT * HH + tid)
                                    : (hb + (size_t)b * TT * HH + (tid - HH));
#pragma unroll 4
    for (int t = 0; t < len; ++t) acc += pl[t] * basep[(size_t)t * HH];
    ctx[(size_t)b * 256 + tid] = acc;
}

// ---------------- final FC: [64,256] @ [256,N] + b ----------------
__global__ __launch_bounds__(256) void fc_kernel(const float* __restrict__ ctx,
                                                 const float* __restrict__ fc_w,
                                                 const float* __restrict__ fc_b,
                                                 float* __restrict__ out) {
    __shared__ __align__(16) float cl[64][256];
    for (int i = threadIdx.x; i < 64 * 256 / 4; i += 256)
        ((float4*)cl)[i] = ((const float4*)ctx)[i];
    __syncthreads();
    int nb = threadIdx.x & 63;
    int bq = threadIdx.x >> 6;
    int n = blockIdx.x * 64 + nb;
    if (n >= NN) return;
    float acc[16];
#pragma unroll
    for (int i = 0; i < 16; ++i) acc[i] = 0.0f;
#pragma unroll 2
    for (int k4 = 0; k4 < 64; ++k4) {
        int k = k4 * 4;
        float w0 = fc_w[(size_t)k * NN + n];
        float w1 = fc_w[(size_t)(k + 1) * NN + n];
        float w2 = fc_w[(size_t)(k + 2) * NN + n];
        float w3 = fc_w[(size_t)(k + 3) * NN + n];
#pragma unroll
        for (int i = 0; i < 16; ++i) {
            float4 cv = *(const float4*)&cl[bq * 16 + i][k];
            acc[i] += cv.x * w0 + cv.y * w1 + cv.z * w2 + cv.w * w3;
        }
    }
    float fb = fc_b[n];
#pragma unroll
    for (int i = 0; i < 16; ++i)
        out[(size_t)(bq * 16 + i) * NN + n] = acc[i] + fb;
}

// ---------------- host launcher ----------------
extern "C" void kernel_launch(void* const* d_in, const int* in_sizes, int n_in,
                              void* d_out, int out_size, void* d_ws, size_t ws_size,
                              hipStream_t stream) {
    const float* x_coords   = (const float*)d_in[0];
    const float* temporal   = (const float*)d_in[1];
    const int*   edge_index = (const int*)d_in[2];
    const float* edge_w     = (const float*)d_in[3];
    const int*   seq        = (const int*)d_in[4];
    const int*   lengths    = (const int*)d_in[5];
    const float* node_emb   = (const float*)d_in[6];
    const float* gcn1_w     = (const float*)d_in[7];
    const float* gcn1_b     = (const float*)d_in[8];
    const float* gcn2_w     = (const float*)d_in[9];
    const float* gcn2_b     = (const float*)d_in[10];
    const float* w_ih_f     = (const float*)d_in[11];
    const float* w_hh_f     = (const float*)d_in[12];
    const float* b_ih_f     = (const float*)d_in[13];
    const float* b_hh_f     = (const float*)d_in[14];
    const float* w_ih_b     = (const float*)d_in[15];
    const float* w_hh_b     = (const float*)d_in[16];
    const float* b_ih_b     = (const float*)d_in[17];
    const float* b_hh_b     = (const float*)d_in[18];
    const float* attn_w     = (const float*)d_in[19];
    const float* attn_b     = (const float*)d_in[20];
    const float* fc_w       = (const float*)d_in[21];
    const float* fc_b       = (const float*)d_in[22];
    float* out = (float*)d_out;

    char* base = (char*)d_ws;
    size_t off = 0;
    auto alloc = [&](size_t nbytes) -> void* {
        void* p = base + off;
        off = (off + nbytes + 255) & ~(size_t)255;
        return p;
    };
    int*   cnt     = (int*)alloc((size_t)2 * NN * 4);  // cnt + degw contiguous (one memset)
    float* degw    = (float*)(cnt + NN);
    float* dinv    = (float*)alloc((size_t)NN * 4);
    int*   rs      = (int*)alloc(((size_t)NN + 1) * 4);
    int*   cursor  = (int*)alloc((size_t)NN * 4);
    int*   partials= (int*)alloc(64 * 4);
    int*   ssrc    = (int*)alloc((size_t)NE * 4);
    float* sw      = (float*)alloc((size_t)NE * 4);
    float* h1      = (float*)alloc((size_t)NN * GH * 4);
    float* z1      = (float*)alloc((size_t)NN * GH * 4);
    float* a2      = h1;  // h1 dead after agg1
    float* z2      = (float*)alloc((size_t)NN * EMB * 4);
    float* se      = (float*)alloc((size_t)BB * TT * EMB * 4);
    float* xpf     = (float*)alloc((size_t)TT * BB * G4 * 4);
    float* xpb     = (float*)alloc((size_t)TT * BB * G4 * 4);
    float* hfo     = (float*)alloc((size_t)BB * TT * HH * 4);
    float* hbo     = (float*)alloc((size_t)BB * TT * HH * 4);
    float* ctx     = (float*)alloc((size_t)BB * 256 * 4);
    (void)ws_size; (void)in_sizes; (void)n_in; (void)out_size;

    hipMemsetAsync(cnt, 0, (size_t)2 * NN * 4, stream);

    hist_kernel<<<(NE + 255) / 256, 256, 0, stream>>>(edge_index, edge_w, cnt, degw);
    dinv_kernel<<<(NN + 255) / 256, 256, 0, stream>>>(degw, dinv);
    const int nblk = (NN + 1023) / 1024;  // 49
    scan1_kernel<<<nblk, 1024, 0, stream>>>(cnt, rs, partials);
    scan2_kernel<<<1, 64, 0, stream>>>(partials, nblk);
    scan3_kernel<<<nblk, 1024, 0, stream>>>(partials, rs, cursor);
    fill_kernel<<<(NE + 255) / 256, 256, 0, stream>>>(edge_index, edge_w, dinv, cursor, ssrc, sw);

    gemm1_kernel<<<(NN + 255) / 256, 256, 0, stream>>>(x_coords, temporal, node_emb, gcn1_w, h1);
    agg_kernel<<<(NN + 3) / 4, 256, 0, stream>>>(h1, rs, ssrc, sw, dinv, gcn1_b, 1, z1);
    agg_kernel<<<(NN + 3) / 4, 256, 0, stream>>>(z1, rs, ssrc, sw, dinv, (const float*)nullptr, 0, a2);
    gemm2_kernel<<<dim3((NN + 255) / 256, 2), 256, 0, stream>>>(a2, gcn2_w, gcn2_b, z2);

    gather_kernel<<<(BB * TT * 32 + 255) / 256, 256, 0, stream>>>(seq, z2, se);
    pregemm_kernel<<<dim3((TT * BB + 1023) / 1024, G4 / 8, 2), 256, 0, stream>>>(
        se, w_ih_f, w_ih_b, b_ih_f, b_hh_f, b_ih_b, b_hh_b, lengths, xpf, xpb);
    lstm_kernel<<<BB * 2, 1024, 0, stream>>>(xpf, xpb, w_hh_f, w_hh_b, lengths, hfo, hbo);
    attn_kernel<<<BB, 256, 0, stream>>>(hfo, hbo, attn_w, attn_b, lengths, ctx);
    fc_kernel<<<(NN + 63) / 64, 256, 0, stream>>>(ctx, fc_w, fc_b, out);
}

// Round 6
// 642.307 us; speedup vs baseline: 1.2047x; 1.1897x over previous
//
#include <hip/hip_runtime.h>
#include <math.h>

#define NN 50000
#define NE 800000
#define EMB 128
#define GH 64
#define BB 64
#define TT 200
#define HH 128
#define G4 512
#define IND 134
#define PM 128
#define PO 128

__device__ __forceinline__ float sigf(float x) { return 1.0f / (1.0f + __expf(-x)); }
__device__ __forceinline__ float tanhf_(float x) { return 1.0f - 2.0f / (__expf(2.0f * x) + 1.0f); }
__device__ __forceinline__ void fma4(float4& a, float s, const float4 w) {
    a.x += s * w.x; a.y += s * w.y; a.z += s * w.z; a.w += s * w.w;
}

// ---------------- CSR build ----------------
__global__ void hist_kernel(const int* __restrict__ ei, const float* __restrict__ ew,
                            int* __restrict__ cnt, float* __restrict__ degw) {
    int e = blockIdx.x * 256 + threadIdx.x;
    if (e >= NE) return;
    int d = ei[NE + e];
    atomicAdd(&cnt[d], 1);
    atomicAdd(&degw[d], ew[e]);
}

__global__ void dinv_kernel(const float* __restrict__ degw, float* __restrict__ dinv) {
    int n = blockIdx.x * 256 + threadIdx.x;
    if (n >= NN) return;
    dinv[n] = rsqrtf(degw[n] + 1.0f);   // +1 self loop
}

__global__ __launch_bounds__(1024) void scan1_kernel(const int* __restrict__ cnt,
                                                     int* __restrict__ rs, int* __restrict__ partials) {
    __shared__ int s[1024];
    int gid = blockIdx.x * 1024 + threadIdx.x;
    int v = (gid < NN) ? cnt[gid] : 0;
    s[threadIdx.x] = v;
    __syncthreads();
    for (int off = 1; off < 1024; off <<= 1) {
        int add = (threadIdx.x >= (unsigned)off) ? s[threadIdx.x - off] : 0;
        __syncthreads();
        s[threadIdx.x] += add;
        __syncthreads();
    }
    if (gid < NN) rs[gid] = s[threadIdx.x] - v;  // exclusive
    if (threadIdx.x == 1023) partials[blockIdx.x] = s[1023];
}

__global__ void scan2_kernel(int* __restrict__ partials, int nblk) {
    if (threadIdx.x == 0) {
        int acc = 0;
        for (int i = 0; i < nblk; ++i) { int v = partials[i]; partials[i] = acc; acc += v; }
    }
}

__global__ __launch_bounds__(1024) void scan3_kernel(const int* __restrict__ partials,
                                                     int* __restrict__ rs, int* __restrict__ cursor) {
    int gid = blockIdx.x * 1024 + threadIdx.x;
    if (gid < NN) {
        int v = rs[gid] + partials[gid >> 10];
        rs[gid] = v;
        cursor[gid] = v;
    }
    if (gid == 0) rs[NN] = NE;
}

__global__ void fill_kernel(const int* __restrict__ ei, const float* __restrict__ ew,
                            const float* __restrict__ dinv, int* __restrict__ cursor,
                            int* __restrict__ ssrc, float* __restrict__ sw) {
    int e = blockIdx.x * 256 + threadIdx.x;
    if (e >= NE) return;
    int s = ei[e], d = ei[NE + e];
    int pos = atomicAdd(&cursor[d], 1);
    ssrc[pos] = s;
    sw[pos] = ew[e] * dinv[s] * dinv[d];
}

// ---------------- GCN layer 1 GEMM (fused concat, 134 -> 64) ----------------
__global__ __launch_bounds__(256) void gemm1_kernel(const float* __restrict__ coords,
                                                    const float* __restrict__ temporal,
                                                    const float* __restrict__ emb,
                                                    const float* __restrict__ W1,
                                                    float* __restrict__ h1) {
    __shared__ __align__(16) float wl[IND][GH];
    for (int i = threadIdx.x; i < IND * GH / 4; i += 256)
        ((float4*)wl)[i] = ((const float4*)W1)[i];
    __syncthreads();
    int n = blockIdx.x * 256 + threadIdx.x;
    if (n >= NN) return;
    float4 acc[16];
    float c0 = coords[2 * n], c1 = coords[2 * n + 1];
#pragma unroll
    for (int j = 0; j < 16; ++j) {
        float4 wa = *(const float4*)&wl[0][j * 4];
        float4 wb = *(const float4*)&wl[1][j * 4];
        float4 a;
        a.x = c0 * wa.x + c1 * wb.x; a.y = c0 * wa.y + c1 * wb.y;
        a.z = c0 * wa.z + c1 * wb.z; a.w = c0 * wa.w + c1 * wb.w;
        acc[j] = a;
    }
    const float4* er = (const float4*)(emb + (size_t)n * EMB);
#pragma unroll 2
    for (int k4 = 0; k4 < 32; ++k4) {
        float4 v = er[k4];
        int k = 2 + k4 * 4;
#pragma unroll
        for (int j = 0; j < 16; ++j) {
            fma4(acc[j], v.x, *(const float4*)&wl[k][j * 4]);
            fma4(acc[j], v.y, *(const float4*)&wl[k + 1][j * 4]);
            fma4(acc[j], v.z, *(const float4*)&wl[k + 2][j * 4]);
            fma4(acc[j], v.w, *(const float4*)&wl[k + 3][j * 4]);
        }
    }
    float t0 = temporal[4 * n], t1 = temporal[4 * n + 1], t2 = temporal[4 * n + 2], t3 = temporal[4 * n + 3];
#pragma unroll
    for (int j = 0; j < 16; ++j) {
        fma4(acc[j], t0, *(const float4*)&wl[130][j * 4]);
        fma4(acc[j], t1, *(const float4*)&wl[131][j * 4]);
        fma4(acc[j], t2, *(const float4*)&wl[132][j * 4]);
        fma4(acc[j], t3, *(const float4*)&wl[133][j * 4]);
        *(float4*)&h1[(size_t)n * GH + j * 4] = acc[j];
    }
}

// ---------------- symmetric-norm aggregation (64 features, CSR) ----------------
__global__ __launch_bounds__(256) void agg_kernel(const float* __restrict__ hin,
                                                  const int* __restrict__ rs,
                                                  const int* __restrict__ ssrc,
                                                  const float* __restrict__ sw,
                                                  const float* __restrict__ dinv,
                                                  const float* __restrict__ bias, int relu,
                                                  float* __restrict__ hout) {
    int lane = threadIdx.x & 63;
    int wid = threadIdx.x >> 6;
    int n = blockIdx.x * 4 + wid;
    if (n >= NN) return;
    float dv = dinv[n];
    float acc = hin[(size_t)n * GH + lane] * (dv * dv);  // self loop
    int i = rs[n], e1 = rs[n + 1];
    for (; i + 3 < e1; i += 4) {
        int s0 = ssrc[i], s1 = ssrc[i + 1], s2 = ssrc[i + 2], s3 = ssrc[i + 3];
        float w0 = sw[i], w1 = sw[i + 1], w2 = sw[i + 2], w3 = sw[i + 3];
        float a0 = hin[(size_t)s0 * GH + lane];
        float a1 = hin[(size_t)s1 * GH + lane];
        float a2 = hin[(size_t)s2 * GH + lane];
        float a3 = hin[(size_t)s3 * GH + lane];
        acc += a0 * w0 + a1 * w1 + a2 * w2 + a3 * w3;
    }
    for (; i < e1; ++i) acc += hin[(size_t)ssrc[i] * GH + lane] * sw[i];
    if (bias) acc += bias[lane];
    if (relu) acc = fmaxf(acc, 0.0f);
    hout[(size_t)n * GH + lane] = acc;
}

// ---------------- GCN layer 2 GEMM (64 -> 128) + bias ----------------
__global__ __launch_bounds__(256) void gemm2_kernel(const float* __restrict__ a2,
                                                    const float* __restrict__ W2,
                                                    const float* __restrict__ b2,
                                                    float* __restrict__ z2) {
    __shared__ __align__(16) float wl[GH][64];
    int j0 = blockIdx.y * 64;
    for (int i = threadIdx.x; i < GH * 16; i += 256) {
        int k = i >> 4, j4 = i & 15;
        *(float4*)&wl[k][j4 * 4] = *(const float4*)&W2[(size_t)k * EMB + j0 + j4 * 4];
    }
    __syncthreads();
    int n = blockIdx.x * 256 + threadIdx.x;
    if (n >= NN) return;
    float4 acc[16];
#pragma unroll
    for (int j = 0; j < 16; ++j) acc[j] = *(const float4*)&b2[j0 + j * 4];
    const float4* ar = (const float4*)(a2 + (size_t)n * GH);
#pragma unroll 2
    for (int k4 = 0; k4 < 16; ++k4) {
        float4 v = ar[k4];
        int k = k4 * 4;
#pragma unroll
        for (int j = 0; j < 16; ++j) {
            fma4(acc[j], v.x, *(const float4*)&wl[k][j * 4]);
            fma4(acc[j], v.y, *(const float4*)&wl[k + 1][j * 4]);
            fma4(acc[j], v.z, *(const float4*)&wl[k + 2][j * 4]);
            fma4(acc[j], v.w, *(const float4*)&wl[k + 3][j * 4]);
        }
    }
#pragma unroll
    for (int j = 0; j < 16; ++j)
        *(float4*)&z2[(size_t)n * EMB + j0 + j * 4] = acc[j];
}

// ---------------- gather sequence embeddings ----------------
__global__ void gather_kernel(const int* __restrict__ seq, const float* __restrict__ z2,
                              float* __restrict__ se) {
    int idx = blockIdx.x * 256 + threadIdx.x;
    if (idx >= BB * TT * 32) return;
    int r = idx >> 5, q = idx & 31;
    int node = seq[r];
    ((float4*)se)[(size_t)r * 32 + q] = ((const float4*)z2)[(size_t)node * 32 + q];
}

// ---------------- pre-GEMM v3: tiled GEMM [12800 x 128] @ [128 x 512]^T ----------------
// R5 post-mortem: o-groups in blockIdx.y re-read se 64x from HBM (FETCH 194MB,
// 237us). v3: 128x128 tile per block, BOTH operands in LDS (64+64 KB), thread
// = 8m x 8o register tile, se re-read only 4x/dir. XOR-swizzled LDS cols
// (col4 ^ (row>>3)&7 for W, &3 for x) break the structural 16-way bank
// conflict (any float4 pad x 8-row lane stride = 0 mod 32 banks).
__global__ __launch_bounds__(256) void pregemm_kernel(const float* __restrict__ se,
                                                      const float* __restrict__ w_ih_f,
                                                      const float* __restrict__ w_ih_b,
                                                      const float* __restrict__ b_ih_f,
                                                      const float* __restrict__ b_hh_f,
                                                      const float* __restrict__ b_ih_b,
                                                      const float* __restrict__ b_hh_b,
                                                      const int* __restrict__ lengths,
                                                      float* __restrict__ xpf,
                                                      float* __restrict__ xpb) {
    int dir = blockIdx.z;
    const float* w_ih = dir ? w_ih_b : w_ih_f;
    int o0 = blockIdx.y * PO;
    int m0 = blockIdx.x * PM;
    __shared__ __align__(16) float xs[PM][EMB];
    __shared__ __align__(16) float ws[PO][EMB];
    __shared__ float bsh[PO];
    int tid = threadIdx.x;
#pragma unroll
    for (int i = 0; i < 16; ++i) {          // stage W (swizzled)
        int idx = i * 256 + tid;
        int row = idx >> 5, c4 = idx & 31;
        float4 v = *(const float4*)&w_ih[(size_t)(o0 + row) * EMB + c4 * 4];
        *(float4*)&ws[row][(c4 ^ ((row >> 3) & 7)) * 4] = v;
    }
    if (tid < PO) bsh[tid] = dir ? (b_ih_b[o0 + tid] + b_hh_b[o0 + tid])
                                 : (b_ih_f[o0 + tid] + b_hh_f[o0 + tid]);
#pragma unroll
    for (int i = 0; i < 16; ++i) {          // stage x (swizzled)
        int idx = i * 256 + tid;
        int r = idx >> 5, c4 = idx & 31;
        int m = m0 + r;
        int t = m >> 6, b = m & 63;
        int tsrc = t;
        if (dir) { int len = lengths[b]; tsrc = (t < len) ? (len - 1 - t) : t; }
        float4 v = *(const float4*)&se[((size_t)b * TT + tsrc) * EMB + c4 * 4];
        *(float4*)&xs[r][(c4 ^ ((r >> 3) & 3)) * 4] = v;
    }
    __syncthreads();
    int mt = tid >> 4, ot = tid & 15;   // each 0..15
    int mswz = mt & 3, oswz = ot & 7;
    float acc[8][8];
#pragma unroll
    for (int mi = 0; mi < 8; ++mi)
#pragma unroll
        for (int oi = 0; oi < 8; ++oi) acc[mi][oi] = 0.0f;
    for (int k4 = 0; k4 < 32; ++k4) {
        int xk = (k4 ^ mswz) * 4;
        int wk = (k4 ^ oswz) * 4;
        float4 xv[8], wv[8];
#pragma unroll
        for (int mi = 0; mi < 8; ++mi) xv[mi] = *(const float4*)&xs[mt * 8 + mi][xk];
#pragma unroll
        for (int oi = 0; oi < 8; ++oi) wv[oi] = *(const float4*)&ws[ot * 8 + oi][wk];
#pragma unroll
        for (int mi = 0; mi < 8; ++mi)
#pragma unroll
            for (int oi = 0; oi < 8; ++oi)
                acc[mi][oi] += xv[mi].x * wv[oi].x + xv[mi].y * wv[oi].y
                             + xv[mi].z * wv[oi].z + xv[mi].w * wv[oi].w;
    }
    float* xp = dir ? xpb : xpf;
#pragma unroll
    for (int mi = 0; mi < 8; ++mi) {
        int m = m0 + mt * 8 + mi;
        int ob = ot * 8;
        float4 oa = make_float4(acc[mi][0] + bsh[ob + 0], acc[mi][1] + bsh[ob + 1],
                                acc[mi][2] + bsh[ob + 2], acc[mi][3] + bsh[ob + 3]);
        float4 obv = make_float4(acc[mi][4] + bsh[ob + 4], acc[mi][5] + bsh[ob + 5],
                                 acc[mi][6] + bsh[ob + 6], acc[mi][7] + bsh[ob + 7]);
        *(float4*)&xp[(size_t)m * G4 + o0 + ob] = oa;
        *(float4*)&xp[(size_t)m * G4 + o0 + ob + 4] = obv;
    }
}

// ---------------- LSTM recurrence (Structure Z) ----------------
// 1024 threads/chain. Thread = (u = tid&127, kq = tid>>7): computes partial
// pre-activations for ALL 4 gates of unit u over k in [16kq,16kq+16).
// W/thread = 64 floats (16 float4, static idx); no butterfly; h-read is
// wave-uniform b128 broadcast (4/thread); partials combined by 2 waves in
// phase B; part kq-dim padded to 9 to spread LDS banks.
__global__ __launch_bounds__(1024, 4) void lstm_kernel(const float* __restrict__ xpf,
                                                       const float* __restrict__ xpb,
                                                       const float* __restrict__ w_hh_f,
                                                       const float* __restrict__ w_hh_b,
                                                       const int* __restrict__ lengths,
                                                       float* __restrict__ hfo,
                                                       float* __restrict__ hbo) {
    int chain = blockIdx.x;
    int dir = chain & 1, b = chain >> 1;
    const float* w_hh = dir ? w_hh_b : w_hh_f;
    const float* xp = dir ? xpb : xpf;
    float* ho = dir ? hbo : hfo;
    int tid = threadIdx.x;
    int u = tid & 127;
    int kq = tid >> 7;    // 0..7
    int len = lengths[b];

    float4 W[4][4];
#pragma unroll
    for (int g = 0; g < 4; ++g)
#pragma unroll
        for (int j4 = 0; j4 < 4; ++j4)
            W[g][j4] = *(const float4*)&w_hh[(size_t)(g * HH + u) * HH + kq * 16 + j4 * 4];

    __shared__ __align__(16) float hl[HH];
    __shared__ __align__(16) float part[HH][9][4];   // [u][kq(pad 9)][gate]
    if (tid < HH) hl[tid] = 0.0f;
    __syncthreads();

    float cst = 0.0f;
    float x0 = 0.f, x1 = 0.f, x2 = 0.f, x3 = 0.f;
    const float* xpt = xp + (size_t)b * G4 + u;
    if (tid < HH && len > 0) {
        x0 = xpt[0]; x1 = xpt[HH]; x2 = xpt[2 * HH]; x3 = xpt[3 * HH];
    }
    for (int t = 0; t < len; ++t) {
        // phase A: all 16 waves; uniform h broadcast reads
        const float4* h4 = (const float4*)&hl[kq * 16];
        float a0 = 0.f, a1 = 0.f, a2 = 0.f, a3 = 0.f;
#pragma unroll
        for (int j4 = 0; j4 < 4; ++j4) {
            float4 hv = h4[j4];
            a0 += W[0][j4].x * hv.x + W[0][j4].y * hv.y + W[0][j4].z * hv.z + W[0][j4].w * hv.w;
            a1 += W[1][j4].x * hv.x + W[1][j4].y * hv.y + W[1][j4].z * hv.z + W[1][j4].w * hv.w;
            a2 += W[2][j4].x * hv.x + W[2][j4].y * hv.y + W[2][j4].z * hv.z + W[2][j4].w * hv.w;
            a3 += W[3][j4].x * hv.x + W[3][j4].y * hv.y + W[3][j4].z * hv.z + W[3][j4].w * hv.w;
        }
        *(float4*)&part[u][kq][0] = make_float4(a0, a1, a2, a3);
        __syncthreads();
        // phase B: 2 waves finish unit u
        if (tid < HH) {
            float n0 = 0.f, n1 = 0.f, n2 = 0.f, n3 = 0.f;
            if (t + 1 < len) {
                const float* xn = xpt + (size_t)(t + 1) * (BB * G4);
                n0 = xn[0]; n1 = xn[HH]; n2 = xn[2 * HH]; n3 = xn[3 * HH];
            }
            float s0 = x0, s1 = x1, s2 = x2, s3 = x3;
#pragma unroll
            for (int q = 0; q < 8; ++q) {
                float4 p = *(const float4*)&part[u][q][0];
                s0 += p.x; s1 += p.y; s2 += p.z; s3 += p.w;
            }
            float gi = sigf(s0), gf = sigf(s1), gg = tanhf_(s2), go = sigf(s3);
            cst = gf * cst + gi * gg;
            float h = go * tanhf_(cst);
            hl[u] = h;
            int tt = dir ? (len - 1 - t) : t;
            ho[((size_t)b * TT + tt) * HH + u] = h;
            x0 = n0; x1 = n1; x2 = n2; x3 = n3;
        }
        __syncthreads();
    }
}

// ---------------- masked attention pooling ----------------
__global__ __launch_bounds__(256) void attn_kernel(const float* __restrict__ hf,
                                                   const float* __restrict__ hb,
                                                   const float* __restrict__ attn_w,
                                                   const float* __restrict__ attn_b,
                                                   const int* __restrict__ lengths,
                                                   float* __restrict__ ctx) {
    int b = blockIdx.x;
    int tid = threadIdx.x;
    int len = lengths[b];
    __shared__ __align__(16) float wl[256];
    __shared__ float pl[256];
    __shared__ float red[256];
    wl[tid] = attn_w[tid];
    __syncthreads();
    float sc = -3.0e38f;
    if (tid < len) {
        const float4* rf = (const float4*)(hf + ((size_t)b * TT + tid) * HH);
        const float4* rb = (const float4*)(hb + ((size_t)b * TT + tid) * HH);
        const float4* w4 = (const float4*)wl;
        float s = attn_b[0];
        for (int k4 = 0; k4 < 32; ++k4) {
            float4 a = rf[k4], ww = w4[k4];
            s += a.x * ww.x + a.y * ww.y + a.z * ww.z + a.w * ww.w;
        }
        for (int k4 = 0; k4 < 32; ++k4) {
            float4 a = rb[k4], ww = w4[32 + k4];
            s += a.x * ww.x + a.y * ww.y + a.z * ww.z + a.w * ww.w;
        }
        sc = s;
    }
    red[tid] = sc;
    __syncthreads();
    for (int off = 128; off > 0; off >>= 1) {
        if (tid < off) red[tid] = fmaxf(red[tid], red[tid + off]);
        __syncthreads();
    }
    float mx = red[0];
    __syncthreads();
    float e = (tid < len) ? __expf(sc - mx) : 0.0f;
    red[tid] = e;
    __syncthreads();
    for (int off = 128; off > 0; off >>= 1) {
        if (tid < off) red[tid] += red[tid + off];
        __syncthreads();
    }
    float inv = 1.0f / red[0];
    pl[tid] = e * inv;
    __syncthreads();
    float acc = 0.0f;
    const float* basep = (tid < HH) ? (hf + (size_t)b * TT * HH + tid)
                                    : (hb + (size_t)b * TT * HH + (tid - HH));
#pragma unroll 4
    for (int t = 0; t < len; ++t) acc += pl[t] * basep[(size_t)t * HH];
    ctx[(size_t)b * 256 + tid] = acc;
}

// ---------------- final FC: [64,256] @ [256,N] + b ----------------
__global__ __launch_bounds__(256) void fc_kernel(const float* __restrict__ ctx,
                                                 const float* __restrict__ fc_w,
                                                 const float* __restrict__ fc_b,
                                                 float* __restrict__ out) {
    __shared__ __align__(16) float cl[64][256];
    for (int i = threadIdx.x; i < 64 * 256 / 4; i += 256)
        ((float4*)cl)[i] = ((const float4*)ctx)[i];
    __syncthreads();
    int nb = threadIdx.x & 63;
    int bq = threadIdx.x >> 6;
    int n = blockIdx.x * 64 + nb;
    if (n >= NN) return;
    float acc[16];
#pragma unroll
    for (int i = 0; i < 16; ++i) acc[i] = 0.0f;
#pragma unroll 2
    for (int k4 = 0; k4 < 64; ++k4) {
        int k = k4 * 4;
        float w0 = fc_w[(size_t)k * NN + n];
        float w1 = fc_w[(size_t)(k + 1) * NN + n];
        float w2 = fc_w[(size_t)(k + 2) * NN + n];
        float w3 = fc_w[(size_t)(k + 3) * NN + n];
#pragma unroll
        for (int i = 0; i < 16; ++i) {
            float4 cv = *(const float4*)&cl[bq * 16 + i][k];
            acc[i] += cv.x * w0 + cv.y * w1 + cv.z * w2 + cv.w * w3;
        }
    }
    float fb = fc_b[n];
#pragma unroll
    for (int i = 0; i < 16; ++i)
        out[(size_t)(bq * 16 + i) * NN + n] = acc[i] + fb;
}

// ---------------- host launcher ----------------
extern "C" void kernel_launch(void* const* d_in, const int* in_sizes, int n_in,
                              void* d_out, int out_size, void* d_ws, size_t ws_size,
                              hipStream_t stream) {
    const float* x_coords   = (const float*)d_in[0];
    const float* temporal   = (const float*)d_in[1];
    const int*   edge_index = (const int*)d_in[2];
    const float* edge_w     = (const float*)d_in[3];
    const int*   seq        = (const int*)d_in[4];
    const int*   lengths    = (const int*)d_in[5];
    const float* node_emb   = (const float*)d_in[6];
    const float* gcn1_w     = (const float*)d_in[7];
    const float* gcn1_b     = (const float*)d_in[8];
    const float* gcn2_w     = (const float*)d_in[9];
    const float* gcn2_b     = (const float*)d_in[10];
    const float* w_ih_f     = (const float*)d_in[11];
    const float* w_hh_f     = (const float*)d_in[12];
    const float* b_ih_f     = (const float*)d_in[13];
    const float* b_hh_f     = (const float*)d_in[14];
    const float* w_ih_b     = (const float*)d_in[15];
    const float* w_hh_b     = (const float*)d_in[16];
    const float* b_ih_b     = (const float*)d_in[17];
    const float* b_hh_b     = (const float*)d_in[18];
    const float* attn_w     = (const float*)d_in[19];
    const float* attn_b     = (const float*)d_in[20];
    const float* fc_w       = (const float*)d_in[21];
    const float* fc_b       = (const float*)d_in[22];
    float* out = (float*)d_out;

    char* base = (char*)d_ws;
    size_t off = 0;
    auto alloc = [&](size_t nbytes) -> void* {
        void* p = base + off;
        off = (off + nbytes + 255) & ~(size_t)255;
        return p;
    };
    int*   cnt     = (int*)alloc((size_t)2 * NN * 4);  // cnt + degw contiguous (one memset)
    float* degw    = (float*)(cnt + NN);
    float* dinv    = (float*)alloc((size_t)NN * 4);
    int*   rs      = (int*)alloc(((size_t)NN + 1) * 4);
    int*   cursor  = (int*)alloc((size_t)NN * 4);
    int*   partials= (int*)alloc(64 * 4);
    int*   ssrc    = (int*)alloc((size_t)NE * 4);
    float* sw      = (float*)alloc((size_t)NE * 4);
    float* h1      = (float*)alloc((size_t)NN * GH * 4);
    float* z1      = (float*)alloc((size_t)NN * GH * 4);
    float* a2      = h1;  // h1 dead after agg1
    float* z2      = (float*)alloc((size_t)NN * EMB * 4);
    float* se      = (float*)alloc((size_t)BB * TT * EMB * 4);
    float* xpf     = (float*)alloc((size_t)TT * BB * G4 * 4);
    float* xpb     = (float*)alloc((size_t)TT * BB * G4 * 4);
    float* hfo     = (float*)alloc((size_t)BB * TT * HH * 4);
    float* hbo     = (float*)alloc((size_t)BB * TT * HH * 4);
    float* ctx     = (float*)alloc((size_t)BB * 256 * 4);
    (void)ws_size; (void)in_sizes; (void)n_in; (void)out_size;

    hipMemsetAsync(cnt, 0, (size_t)2 * NN * 4, stream);

    hist_kernel<<<(NE + 255) / 256, 256, 0, stream>>>(edge_index, edge_w, cnt, degw);
    dinv_kernel<<<(NN + 255) / 256, 256, 0, stream>>>(degw, dinv);
    const int nblk = (NN + 1023) / 1024;  // 49
    scan1_kernel<<<nblk, 1024, 0, stream>>>(cnt, rs, partials);
    scan2_kernel<<<1, 64, 0, stream>>>(partials, nblk);
    scan3_kernel<<<nblk, 1024, 0, stream>>>(partials, rs, cursor);
    fill_kernel<<<(NE + 255) / 256, 256, 0, stream>>>(edge_index, edge_w, dinv, cursor, ssrc, sw);

    gemm1_kernel<<<(NN + 255) / 256, 256, 0, stream>>>(x_coords, temporal, node_emb, gcn1_w, h1);
    agg_kernel<<<(NN + 3) / 4, 256, 0, stream>>>(h1, rs, ssrc, sw, dinv, gcn1_b, 1, z1);
    agg_kernel<<<(NN + 3) / 4, 256, 0, stream>>>(z1, rs, ssrc, sw, dinv, (const float*)nullptr, 0, a2);
    gemm2_kernel<<<dim3((NN + 255) / 256, 2), 256, 0, stream>>>(a2, gcn2_w, gcn2_b, z2);

    gather_kernel<<<(BB * TT * 32 + 255) / 256, 256, 0, stream>>>(seq, z2, se);
    pregemm_kernel<<<dim3(TT * BB / PM, G4 / PO, 2), 256, 0, stream>>>(
        se, w_ih_f, w_ih_b, b_ih_f, b_hh_f, b_ih_b, b_hh_b, lengths, xpf, xpb);
    lstm_kernel<<<BB * 2, 1024, 0, stream>>>(xpf, xpb, w_hh_f, w_hh_b, lengths, hfo, hbo);
    attn_kernel<<<BB, 256, 0, stream>>>(hfo, hbo, attn_w, attn_b, lengths, ctx);
    fc_kernel<<<(NN + 63) / 64, 256, 0, stream>>>(ctx, fc_w, fc_b, out);
}